// Round 4
// baseline (228.936 us; speedup 1.0000x reference)
//
#include <hip/hip_runtime.h>

// x: (B=8, L=8192, D=512) fp32.  out: (B, 2048, D) fp32.
// out[b,i,d] = (sum_{l<=4(i+1)-1} x[b,l,d]) / (4(i+1))
//
// Two-pass chunked scan, x read exactly once from HBM:
//   phase 1: stream 32-row chunk (8 loads in flight); write UNSCALED local
//            cumsum checkpoints (rows 3,7,..,31) straight into d_out;
//            chunk total -> d_ws.
//   phase 2: exclusive prefix over chunk totals (4 MiB, L2/L3), read back
//            the 8 checkpoints (L3-hot), add prefix, scale, store in place.
// Same-thread RMW per element => no cross-thread hazard; stream ordering
// gives phase1->phase2 visibility.
//
// NC=256 -> 1024 blocks (4 blocks/CU, 4 waves/SIMD) for HBM latency hiding.

#define BB   8
#define LL   8192
#define DD4  128            // D / 4 (float4 granularity)
#define NC   256            // chunks along L
#define CL   (LL / NC)      // 32 rows per chunk
#define OPC  (CL / 4)       // 8 outputs per chunk per column
#define OL   (LL / 4)       // 2048 output rows

__global__ __launch_bounds__(256) void ds_phase1(const float4* __restrict__ x,
                                                 float4* __restrict__ sums,
                                                 float4* __restrict__ out) {
    int tid = blockIdx.x * blockDim.x + threadIdx.x;
    int d4 = tid & (DD4 - 1);
    int c  = (tid >> 7) & (NC - 1);
    int b  = tid >> 15;

    const float4* p = x + (((size_t)b * LL + c * CL) * DD4 + d4);
    float4* o = out + (((size_t)b * OL + c * OPC) * DD4 + d4);

    float sx = 0.f, sy = 0.f, sz = 0.f, sw = 0.f;
    #pragma unroll
    for (int j = 0; j < CL; j += 8) {
        // 8 independent loads in flight before any use
        float4 v0 = p[(j + 0) * DD4];
        float4 v1 = p[(j + 1) * DD4];
        float4 v2 = p[(j + 2) * DD4];
        float4 v3 = p[(j + 3) * DD4];
        float4 v4 = p[(j + 4) * DD4];
        float4 v5 = p[(j + 5) * DD4];
        float4 v6 = p[(j + 6) * DD4];
        float4 v7 = p[(j + 7) * DD4];
        sx += v0.x + v1.x + v2.x + v3.x;
        sy += v0.y + v1.y + v2.y + v3.y;
        sz += v0.z + v1.z + v2.z + v3.z;
        sw += v0.w + v1.w + v2.w + v3.w;
        o[((j >> 2) + 0) * DD4] = make_float4(sx, sy, sz, sw);
        sx += v4.x + v5.x + v6.x + v7.x;
        sy += v4.y + v5.y + v6.y + v7.y;
        sz += v4.z + v5.z + v6.z + v7.z;
        sw += v4.w + v5.w + v6.w + v7.w;
        o[((j >> 2) + 1) * DD4] = make_float4(sx, sy, sz, sw);
    }
    sums[(b * NC + c) * DD4 + d4] = make_float4(sx, sy, sz, sw);
}

__global__ __launch_bounds__(256) void ds_phase2(float4* __restrict__ out,
                                                 const float4* __restrict__ sums) {
    int tid = blockIdx.x * blockDim.x + threadIdx.x;
    int d4 = tid & (DD4 - 1);
    int c  = (tid >> 7) & (NC - 1);
    int b  = tid >> 15;

    // exclusive prefix over preceding chunk totals (wave-uniform trip count;
    // 4 MiB array, L2/L3-served; 4 independent accumulator chains via unroll)
    float rx = 0.f, ry = 0.f, rz = 0.f, rw = 0.f;
    const float4* sp = sums + b * NC * DD4 + d4;
    #pragma unroll 4
    for (int q = 0; q < c; ++q) {
        float4 v = sp[q * DD4];
        rx += v.x; ry += v.y; rz += v.z; rw += v.w;
    }

    float4* o = out + (((size_t)b * OL + c * OPC) * DD4 + d4);
    const int base = c * CL;

    // load all 8 checkpoints first (MLP), then fix up + store in place
    float4 v[OPC];
    #pragma unroll
    for (int k = 0; k < OPC; ++k) v[k] = o[(size_t)k * DD4];
    #pragma unroll
    for (int k = 0; k < OPC; ++k) {
        const float inv = 1.0f / (float)(base + 4 * k + 4);
        o[(size_t)k * DD4] = make_float4((v[k].x + rx) * inv,
                                         (v[k].y + ry) * inv,
                                         (v[k].z + rz) * inv,
                                         (v[k].w + rw) * inv);
    }
}

extern "C" void kernel_launch(void* const* d_in, const int* in_sizes, int n_in,
                              void* d_out, int out_size, void* d_ws, size_t ws_size,
                              hipStream_t stream) {
    const float4* x = (const float4*)d_in[0];
    float4* out = (float4*)d_out;
    float4* sums = (float4*)d_ws;      // B*NC*DD4 float4 = 4 MiB, fully written by phase1

    const int total = BB * NC * DD4;   // 262144 threads
    const int block = 256;
    const int grid  = total / block;   // 1024 blocks

    ds_phase1<<<grid, block, 0, stream>>>(x, sums, out);
    ds_phase2<<<grid, block, 0, stream>>>(out, sums);
}

// Round 6
// 206.182 us; speedup vs baseline: 1.1104x; 1.1104x over previous
//
#include <hip/hip_runtime.h>

// x: (B=8, L=8192, D=512) fp32.  out: (B, 2048, D) fp32.
// out[b,i,d] = (sum_{l<=4(i+1)-1} x[b,l,d]) / (4(i+1))
//
// Two-pass chunked scan (R3 structure — cooperative launch does NOT work in
// this harness, R5), with two micro-fixes:
//   * phase1 reads x via __builtin_nontemporal_load (evict-first): x is
//     never re-read, so don't let its 128 MiB flush the fresh checkpoint/
//     sums lines that phase2 re-reads.
//   * phase2 issues all 16 checkpoint loads BEFORE the prefix loop so they
//     overlap the L2 prefix burst.
//   phase 1: stream 64-row chunk (8 loads in flight); write UNSCALED local
//            cumsum checkpoints into d_out; chunk total -> d_ws (cached).
//   phase 2: exclusive prefix over chunk totals (2 MiB, L2) + in-place
//            scale of the checkpoints.  Same-thread RMW; stream ordering
//            gives phase1->phase2 visibility.

#define BB   8
#define LL   8192
#define DD4  128            // D / 4 (float4 granularity)
#define NC   128            // chunks along L
#define CL   (LL / NC)      // 64 rows per chunk
#define OPC  (CL / 4)       // 16 outputs per chunk per column
#define OL   (LL / 4)       // 2048 output rows

typedef float vf4 __attribute__((ext_vector_type(4)));

__global__ __launch_bounds__(256) void ds_phase1(const vf4* __restrict__ x,
                                                 vf4* __restrict__ sums,
                                                 vf4* __restrict__ out) {
    int tid = blockIdx.x * blockDim.x + threadIdx.x;
    int d4 = tid & (DD4 - 1);
    int c  = (tid >> 7) & (NC - 1);
    int b  = tid >> 14;

    const vf4* p = x + (((size_t)b * LL + c * CL) * DD4 + d4);
    vf4* o = out + (((size_t)b * OL + c * OPC) * DD4 + d4);

    vf4 s = (vf4)0.f;
    #pragma unroll
    for (int j = 0; j < CL; j += 8) {
        // 8 independent NT loads in flight before any use
        vf4 v0 = __builtin_nontemporal_load(&p[(j + 0) * DD4]);
        vf4 v1 = __builtin_nontemporal_load(&p[(j + 1) * DD4]);
        vf4 v2 = __builtin_nontemporal_load(&p[(j + 2) * DD4]);
        vf4 v3 = __builtin_nontemporal_load(&p[(j + 3) * DD4]);
        vf4 v4 = __builtin_nontemporal_load(&p[(j + 4) * DD4]);
        vf4 v5 = __builtin_nontemporal_load(&p[(j + 5) * DD4]);
        vf4 v6 = __builtin_nontemporal_load(&p[(j + 6) * DD4]);
        vf4 v7 = __builtin_nontemporal_load(&p[(j + 7) * DD4]);
        s += v0 + v1 + v2 + v3;
        o[((j >> 2) + 0) * DD4] = s;        // unscaled local cumsum (cached)
        s += v4 + v5 + v6 + v7;
        o[((j >> 2) + 1) * DD4] = s;
    }
    sums[(b * NC + c) * DD4 + d4] = s;      // chunk total (cached)
}

__global__ __launch_bounds__(256) void ds_phase2(vf4* __restrict__ out,
                                                 const vf4* __restrict__ sums) {
    int tid = blockIdx.x * blockDim.x + threadIdx.x;
    int d4 = tid & (DD4 - 1);
    int c  = (tid >> 7) & (NC - 1);
    int b  = tid >> 14;

    vf4* o = out + (((size_t)b * OL + c * OPC) * DD4 + d4);

    // issue all 16 checkpoint loads FIRST so they overlap the prefix loop
    vf4 v[OPC];
    #pragma unroll
    for (int k = 0; k < OPC; ++k) v[k] = o[(size_t)k * DD4];

    // exclusive prefix over preceding chunk totals (wave-uniform c; 2 MiB
    // array, L2-resident; independent accumulations via unroll)
    vf4 r = (vf4)0.f;
    const vf4* sp = sums + b * NC * DD4 + d4;
    #pragma unroll 4
    for (int q = 0; q < c; ++q) r += sp[q * DD4];

    const int base = c * CL;
    #pragma unroll
    for (int k = 0; k < OPC; ++k) {
        const float inv = 1.0f / (float)(base + 4 * k + 4);
        o[(size_t)k * DD4] = (v[k] + r) * inv;
    }
}

extern "C" void kernel_launch(void* const* d_in, const int* in_sizes, int n_in,
                              void* d_out, int out_size, void* d_ws, size_t ws_size,
                              hipStream_t stream) {
    const vf4* x = (const vf4*)d_in[0];
    vf4* out = (vf4*)d_out;
    vf4* sums = (vf4*)d_ws;            // B*NC*DD4 vf4 = 2 MiB, fully written by phase1

    const int total = BB * NC * DD4;   // 131072 threads
    const int block = 256;
    const int grid  = total / block;   // 512 blocks

    ds_phase1<<<grid, block, 0, stream>>>(x, sums, out);
    ds_phase2<<<grid, block, 0, stream>>>(out, sums);
}